// Round 5
// baseline (226.689 us; speedup 1.0000x reference)
//
#include <hip/hip_runtime.h>

#define BS     8192
#define DIM    768
#define NPART  16
#define BM     128
#define BN     128
#define BK     64
#define PCOLS  (BS / NPART)     // 512 cols per partition
#define NJT    (PCOLS / BN)     // 4 col-tiles per block
#define NKT    (DIM / BK)       // 12 k-tiles
#define NEL    ((size_t)BS * DIM)        // 6291456
#define NEL4   (NEL / 4)                 // 1572864 float4 tiles per input
#define CTILE  (2 * NEL4 - 1)            // dst float4 tiles: m in [1, 3145727]

typedef __bf16 bfrag_t __attribute__((ext_vector_type(8)));
typedef float  facc_t  __attribute__((ext_vector_type(4)));

typedef const __attribute__((address_space(1))) void gv_t;
typedef __attribute__((address_space(3))) void lv_t;

__device__ __forceinline__ void gll16(const void* g, void* l) {
  // async global->LDS DMA, 16B/lane; LDS dest = wave-uniform base + lane*16
  __builtin_amdgcn_global_load_lds((gv_t*)g, (lv_t*)l, 16, 0, 0);
}

__device__ __forceinline__ unsigned short f2bf(float f) {
  union { float f; unsigned u; } v; v.f = f;
  unsigned u = v.u;
  return (unsigned short)((u + 0x7FFFu + ((u >> 16) & 1u)) >> 16);  // RNE
}

// ---------------- prep: bf16 convert (both inputs) + diag ----------------
// One wave per row: read nl[row], cd[row] once, write bf16 rows, diag dot.
__global__ void prep_kernel(const float* __restrict__ nl, const float* __restrict__ cd,
                            unsigned short* __restrict__ nlb, unsigned short* __restrict__ cdb,
                            float* __restrict__ dg) {
  const int lane = threadIdx.x & 63;
  const int wave = threadIdx.x >> 6;
  const int row  = blockIdx.x * 4 + wave;
  const size_t rbase = (size_t)row * DIM;
  const float4* ar = reinterpret_cast<const float4*>(nl + rbase);
  const float4* br = reinterpret_cast<const float4*>(cd + rbase);
  ushort4* ba = reinterpret_cast<ushort4*>(nlb + rbase);
  ushort4* bb = reinterpret_cast<ushort4*>(cdb + rbase);

  float s = 0.f;
#pragma unroll
  for (int i = 0; i < 3; ++i) {                 // 192 float4 per row, 3 per lane
    int idx = lane + 64 * i;
    float4 x = ar[idx];
    float4 y = br[idx];
    ushort4 xb, yb;
    xb.x = f2bf(x.x); xb.y = f2bf(x.y); xb.z = f2bf(x.z); xb.w = f2bf(x.w);
    yb.x = f2bf(y.x); yb.y = f2bf(y.y); yb.z = f2bf(y.z); yb.w = f2bf(y.w);
    ba[idx] = xb;
    bb[idx] = yb;
    s += x.x * y.x + x.y * y.y + x.z * y.z + x.w * y.w;
  }
#pragma unroll
  for (int off = 32; off; off >>= 1) s += __shfl_xor(s, off, 64);
  if (lane == 0) dg[row] = s;
}

// concat source: tile i of [cd | nl] as float4
__device__ __forceinline__ float4 cc4(const float4* cd4, const float4* nl4, size_t i) {
  return (i < NEL4) ? cd4[i] : nl4[i - NEL4];
}

// ---------------- fused GEMM (bf16 MFMA) + online lse + aligned output copy ----------------
// block: 256 threads (4 waves, 2x2 of 64x64), tile 128x128, BK=64.
// grid: (NPART, BS/BM) = (16, 64) = 1024 blocks.
// Prologue: dst-aligned grid-stride copy of (cd,nl) -> out[1..2*NEL], zero out[0].
// LDS: XOR-swizzled, unpadded (required by global_load_lds):
//   unit u (16B = 8 bf16) holds global (row=u>>3, c8 = (u&7)^(row&7)).
__global__ __launch_bounds__(256, 4) void gemm_lse_kernel(
    const unsigned short* __restrict__ Abf,
    const unsigned short* __restrict__ Bbf,
    const float* __restrict__ cdf, const float* __restrict__ nlf,
    float* __restrict__ outp,
    float* __restrict__ pm, float* __restrict__ pl) {
  __shared__ __align__(16) unsigned short As[BM * BK];   // 16 KB
  __shared__ __align__(16) unsigned short Bs[BN * BK];   // 16 KB

  const int tid  = threadIdx.x;
  const int lane = tid & 63;
  const int wave = tid >> 6;
  const int wm   = wave >> 1;
  const int wn   = wave & 1;
  const int l15  = lane & 15;
  const int l4   = lane >> 4;
  const int sw   = l15 & 7;        // row-dependent xor for fragment reads
  const int cp   = blockIdx.x;
  const int rb   = blockIdx.y;

  // ---- output copy prologue (dst 16B-aligned; out[4m..4m+3] = concat[4m-1..4m+2]) ----
  {
    const float4* cd4 = reinterpret_cast<const float4*>(cdf);
    const float4* nl4 = reinterpret_cast<const float4*>(nlf);
    const size_t gtid = ((size_t)blockIdx.y * gridDim.x + blockIdx.x) * blockDim.x + tid;
    const size_t nthr = (size_t)gridDim.x * gridDim.y * blockDim.x;   // 262144
    for (size_t m = 1 + gtid; m <= CTILE; m += nthr) {
      float4 A = cc4(cd4, nl4, m - 1);
      float4 B = cc4(cd4, nl4, m);
      float4 d;
      d.x = A.w; d.y = B.x; d.z = B.y; d.w = B.z;
      *reinterpret_cast<float4*>(outp + 4 * m) = d;
    }
    if (gtid == 0) {
      outp[0] = 0.f;                       // loss accumulator (loss kernel atomically adds)
      outp[1] = cdf[0]; outp[2] = cdf[1]; outp[3] = cdf[2];
      outp[2 * NEL] = nlf[NEL - 1];        // last element
    }
  }

  int srow[4], sc8g[4];
#pragma unroll
  for (int t = 0; t < 4; ++t) {
    int u   = wave * 256 + t * 64 + lane;
    srow[t] = u >> 3;
    sc8g[t] = (u & 7) ^ (srow[t] & 7);
  }

  float mrun[4][4], lrun[4][4];
#pragma unroll
  for (int i = 0; i < 4; ++i)
#pragma unroll
    for (int r = 0; r < 4; ++r) { mrun[i][r] = -1e30f; lrun[i][r] = 0.f; }

  for (int jt = 0; jt < NJT; ++jt) {
    facc_t acc[4][4];
#pragma unroll
    for (int mt = 0; mt < 4; ++mt)
#pragma unroll
      for (int nt = 0; nt < 4; ++nt) acc[mt][nt] = (facc_t){0.f, 0.f, 0.f, 0.f};

    for (int kt = 0; kt < NKT; ++kt) {
      __syncthreads();
#pragma unroll
      for (int t = 0; t < 4; ++t) {
        size_t ldso = (size_t)(wave * 256 + t * 64) * 8;  // shorts
        gll16(Abf + (size_t)(rb * BM + srow[t]) * DIM + kt * BK + sc8g[t] * 8, As + ldso);
        gll16(Bbf + (size_t)(cp * PCOLS + jt * BN + srow[t]) * DIM + kt * BK + sc8g[t] * 8, Bs + ldso);
      }
      __syncthreads();

#pragma unroll
      for (int ks = 0; ks < 2; ++ks) {
        const int k8 = ks * 4 + l4;
        bfrag_t af[4], bfv[4];
#pragma unroll
        for (int mt = 0; mt < 4; ++mt) {
          int row = wm * 64 + mt * 16 + l15;
          af[mt] = *reinterpret_cast<const bfrag_t*>(&As[row * BK + (k8 ^ sw) * 8]);
        }
#pragma unroll
        for (int nt = 0; nt < 4; ++nt) {
          int row = wn * 64 + nt * 16 + l15;
          bfv[nt] = *reinterpret_cast<const bfrag_t*>(&Bs[row * BK + (k8 ^ sw) * 8]);
        }
#pragma unroll
        for (int mt = 0; mt < 4; ++mt)
#pragma unroll
          for (int nt = 0; nt < 4; ++nt)
            acc[mt][nt] = __builtin_amdgcn_mfma_f32_16x16x32_bf16(af[mt], bfv[nt], acc[mt][nt], 0, 0, 0);
      }
    }

    // online-lse update (per lane over its own column subset)
#pragma unroll
    for (int mt = 0; mt < 4; ++mt)
#pragma unroll
      for (int r = 0; r < 4; ++r) {
        float v0 = acc[mt][0][r], v1 = acc[mt][1][r], v2 = acc[mt][2][r], v3 = acc[mt][3][r];
        float tm = fmaxf(fmaxf(v0, v1), fmaxf(v2, v3));
        float mn = fmaxf(mrun[mt][r], tm);
        float sc = __expf(mrun[mt][r] - mn);
        lrun[mt][r] = lrun[mt][r] * sc +
                      __expf(v0 - mn) + __expf(v1 - mn) + __expf(v2 - mn) + __expf(v3 - mn);
        mrun[mt][r] = mn;
      }
  }

  // merge across the 16 lanes sharing rows (different column subsets)
#pragma unroll
  for (int mask = 1; mask < 16; mask <<= 1)
#pragma unroll
    for (int mt = 0; mt < 4; ++mt)
#pragma unroll
      for (int r = 0; r < 4; ++r) {
        float om = __shfl_xor(mrun[mt][r], mask, 64);
        float ol = __shfl_xor(lrun[mt][r], mask, 64);
        float mn = fmaxf(mrun[mt][r], om);
        lrun[mt][r] = lrun[mt][r] * __expf(mrun[mt][r] - mn) + ol * __expf(om - mn);
        mrun[mt][r] = mn;
      }

  // combine the two column-half waves via LDS (alias onto As/Bs — done with tiles)
  float* cm = reinterpret_cast<float*>(As);   // [2][BM]
  float* cl = reinterpret_cast<float*>(Bs);   // [2][BM]
  __syncthreads();
  if (l15 == 0) {
#pragma unroll
    for (int mt = 0; mt < 4; ++mt)
#pragma unroll
      for (int r = 0; r < 4; ++r) {
        int rl = wm * 64 + mt * 16 + l4 * 4 + r;
        cm[wn * BM + rl] = mrun[mt][r];
        cl[wn * BM + rl] = lrun[mt][r];
      }
  }
  __syncthreads();
  if (tid < BM) {
    float m0 = cm[tid], l0 = cl[tid];
    float m1 = cm[BM + tid], l1 = cl[BM + tid];
    float mn = fmaxf(m0, m1);
    float ll = l0 * __expf(m0 - mn) + l1 * __expf(m1 - mn);
    size_t g = (size_t)(rb * BM + tid) * NPART + cp;
    pm[g] = mn;
    pl[g] = ll;
  }
}

// ---------------- loss: combine partitions, subtract diag, atomic mean ----------------
// 32 blocks x 256 threads, one row per thread; out[0] pre-zeroed by gemm prologue.
__global__ void loss_kernel(const float* __restrict__ pm, const float* __restrict__ pl,
                            const float* __restrict__ dg, float* __restrict__ out) {
  __shared__ float red[4];
  const int tid = threadIdx.x;
  const int r   = blockIdx.x * 256 + tid;

  const float4* pmr = reinterpret_cast<const float4*>(pm + (size_t)r * NPART);
  const float4* plr = reinterpret_cast<const float4*>(pl + (size_t)r * NPART);

  float m = -1e30f, l = 0.f;
#pragma unroll
  for (int q = 0; q < NPART / 4; ++q) {
    float4 mv = pmr[q];
    float4 lv = plr[q];
#pragma unroll
    for (int k = 0; k < 4; ++k) {
      float m2 = (&mv.x)[k], l2 = (&lv.x)[k];
      float mn = fmaxf(m, m2);
      l = l * __expf(m - mn) + l2 * __expf(m2 - mn);
      m = mn;
    }
  }
  float local = m + __logf(l) - dg[r];

#pragma unroll
  for (int off = 32; off; off >>= 1) local += __shfl_xor(local, off, 64);
  if ((tid & 63) == 0) red[tid >> 6] = local;
  __syncthreads();
  if (tid == 0) {
    float s = red[0] + red[1] + red[2] + red[3];
    atomicAdd(out, s / (float)BS);
  }
}

extern "C" void kernel_launch(void* const* d_in, const int* in_sizes, int n_in,
                              void* d_out, int out_size, void* d_ws, size_t ws_size,
                              hipStream_t stream) {
  const float* nl = (const float*)d_in[0];
  const float* cd = (const float*)d_in[1];
  float* out = (float*)d_out;

  unsigned short* nlb = (unsigned short*)d_ws;       // NEL bf16
  unsigned short* cdb = nlb + NEL;                   // NEL bf16
  float* pm = (float*)(cdb + NEL);                   // BS*NPART
  float* pl = pm + (size_t)BS * NPART;               // BS*NPART
  float* dg = pl + (size_t)BS * NPART;               // BS

  // out = [loss, code_vec copy, nl_vec copy]; copies + out[0]=0 done in gemm prologue
  prep_kernel<<<BS / 4, 256, 0, stream>>>(nl, cd, nlb, cdb, dg);
  gemm_lse_kernel<<<dim3(NPART, BS / BM), 256, 0, stream>>>(nlb, cdb, cd, nl, out, pm, pl);
  loss_kernel<<<BS / 256, 256, 0, stream>>>(pm, pl, dg, out);
}